// Round 11
// baseline (87.941 us; speedup 1.0000x reference)
//
#include <hip/hip_runtime.h>
#include <math.h>

#define N 8192
#define D 128
#define KSEL 16
#define CH 256            // columns per chunk (per block)
#define NC (N / CH)       // 32 chunks per row
#define BM 128            // rows per block (4 waves x 2 sets x 16)
#define PH 4              // phases per chunk, 64 cols each
#define CPC 2             // candidates per chunk per row (top-2 per 256 cols)
#define NEG_INF_F (-1e30f)
#define LOG2E 1.44269504f
#define LN2 0.69314718f

typedef __attribute__((ext_vector_type(8))) short short8;
typedef __attribute__((ext_vector_type(4))) float f32x4;
typedef __attribute__((ext_vector_type(2))) unsigned short ush2;

static __device__ __forceinline__ unsigned short f2bf(float f) {
    unsigned u = __float_as_uint(f);
    u += 0x7FFF + ((u >> 16) & 1);          // RNE
    return (unsigned short)(u >> 16);
}

// raw v_exp_f32 (2^x). Domain here is |x| <= ~1.45, so the compiler's
// denormal-range fixup (cmp/cndmask/add/ldexp around v_exp_f32) is dead
// weight -- skip it. VALU->VALU deps are HW-interlocked, no waits needed.
static __device__ __forceinline__ float exp2_raw(float x) {
    float r;
    asm("v_exp_f32 %0, %1" : "=v"(r) : "v"(x));
    return r;
}

// async global->LDS, 16B per lane, LDS dest = uniform base + lane*16
#define GLOAD_LDS(gsrc, ldst)                                                     \
    __builtin_amdgcn_global_load_lds(                                             \
        (const __attribute__((address_space(1))) unsigned int*)(const void*)(gsrc),\
        (__attribute__((address_space(3))) unsigned int*)(void*)(ldst), 16, 0, 0)

// ---------- kernel 1: normalize rows; xnB = bf16(xn), xnA = bf16(log2e*xn) ----------
__global__ void k_normalize(const float* __restrict__ x,
                            unsigned short* __restrict__ xnA,
                            unsigned short* __restrict__ xnB,
                            float* __restrict__ out) {
    if (blockIdx.x == 0 && threadIdx.x == 0) out[0] = 0.f;   // accumulator init
    int row = blockIdx.x * 4 + (threadIdx.x >> 6);
    int lane = threadIdx.x & 63;
    const float2* x2 = (const float2*)(x + (size_t)row * D);
    float2 a = x2[lane];
    float s = fmaf(a.x, a.x, a.y * a.y);
#pragma unroll
    for (int off = 32; off > 0; off >>= 1) s += __shfl_xor(s, off, 64);
    float inv = rsqrtf(s);
    ush2 hb, ha;
    hb.x = f2bf(a.x * inv);
    hb.y = f2bf(a.y * inv);
    ha.x = f2bf(a.x * inv * LOG2E);
    ha.y = f2bf(a.y * inv * LOG2E);
    *(ush2*)(xnB + (size_t)row * D + lane * 2) = hb;
    *(ush2*)(xnA + (size_t)row * D + lane * 2) = ha;
}

// ---------- kernel 2: LDS-staged MFMA, 2 A-row-sets per wave ----------
// Each B fragment (one ds_read_b128) feeds TWO MFMAs (row-sets +0 and +64).
// A-operand pre-scaled by log2(e): acc = log2e*S, exp-sum is a bare raw
// v_exp_f32, top-k order unchanged (merge multiplies topsum by ln2).
// Phases of 64 cols (4 tiles), double-buffered via global_load_lds with
// LDS slot = consuming lane index (linear, conflict-free, no swizzle).
// Epilogue per element: exp2(1) + add(1) + top-2 insert via max+fmed3 (2)
// = 4 insts. Emits top-2 per 256-col chunk (64 candidates/row total).
// Diagonal stays IN exp-sum (reference keeps self) and IN candidates
// (scaled S_ii ~ 1.44 is the global candidate max; merge drops rank 0).
__global__ __launch_bounds__(256, 5) void k_tiles(const unsigned short* __restrict__ xnA,
                                                  const unsigned short* __restrict__ xnB,
                                                  float* __restrict__ cs,
                                                  float* __restrict__ ct) {
    // [buf][tile][slice][lane][8 bf16] = 32 KB
    __shared__ unsigned short Bsh[2][4][4][64][8];

    const int tid = threadIdx.x;
    const int w = tid >> 6;
    const int l = tid & 63;
    const int r = l & 15;                    // col-within-tile / A-row lane
    const int p = l >> 4;                    // k-group; output rows p*4+q
    const int i0 = blockIdx.x * BM;
    const int j0 = blockIdx.y * CH;
    const int by = blockIdx.y;

    // A fragments, two row-sets: rows i0 + set*64 + w*16 + r
    const unsigned short* ap = xnA + (size_t)(i0 + w * 16 + r) * D + p * 8;
    short8 af0 = *(const short8*)(ap);
    short8 af1 = *(const short8*)(ap + 32);
    short8 af2 = *(const short8*)(ap + 64);
    short8 af3 = *(const short8*)(ap + 96);
    const unsigned short* gp = ap + (size_t)64 * D;
    short8 ag0 = *(const short8*)(gp);
    short8 ag1 = *(const short8*)(gp + 32);
    short8 ag2 = *(const short8*)(gp + 64);
    short8 ag3 = *(const short8*)(gp + 96);

    float sE[2][4], c0[2][4], c1[2][4];
#pragma unroll
    for (int s2 = 0; s2 < 2; ++s2)
#pragma unroll
        for (int q = 0; q < 4; ++q) {
            sE[s2][q] = 0.f;
            c0[s2][q] = c1[s2][q] = NEG_INF_F;
        }

    // staging source: wave w stages slice w; lane l fetches
    // B[j0 + ph*64 + tile*16 + (l&15)][k = (l>>4)*8 + w*32]
    const unsigned short* sbase = xnB + (size_t)(j0 + r) * D + p * 8 + w * 32;

    // prologue: stage phase 0 into buf 0
#pragma unroll
    for (int tt = 0; tt < 4; ++tt)
        GLOAD_LDS(sbase + (size_t)tt * (16 * D), &Bsh[0][tt][w][0][0]);
    __syncthreads();

    for (int ph = 0; ph < PH; ++ph) {
        const int buf = ph & 1;
        if (ph < PH - 1) {
            const unsigned short* s1 = sbase + (size_t)(ph + 1) * (64 * D);
#pragma unroll
            for (int tt = 0; tt < 4; ++tt)
                GLOAD_LDS(s1 + (size_t)tt * (16 * D), &Bsh[buf ^ 1][tt][w][0][0]);
        }
#pragma unroll
        for (int tt = 0; tt < 4; ++tt) {
            short8 b0 = *(const short8*)&Bsh[buf][tt][0][l][0];
            short8 b1 = *(const short8*)&Bsh[buf][tt][1][l][0];
            short8 b2 = *(const short8*)&Bsh[buf][tt][2][l][0];
            short8 b3 = *(const short8*)&Bsh[buf][tt][3][l][0];
            f32x4 a0 = {0.f, 0.f, 0.f, 0.f};
            f32x4 a1 = {0.f, 0.f, 0.f, 0.f};
            a0 = __builtin_amdgcn_mfma_f32_16x16x32_bf16(af0, b0, a0, 0, 0, 0);
            a0 = __builtin_amdgcn_mfma_f32_16x16x32_bf16(af1, b1, a0, 0, 0, 0);
            a0 = __builtin_amdgcn_mfma_f32_16x16x32_bf16(af2, b2, a0, 0, 0, 0);
            a0 = __builtin_amdgcn_mfma_f32_16x16x32_bf16(af3, b3, a0, 0, 0, 0);
            a1 = __builtin_amdgcn_mfma_f32_16x16x32_bf16(ag0, b0, a1, 0, 0, 0);
            a1 = __builtin_amdgcn_mfma_f32_16x16x32_bf16(ag1, b1, a1, 0, 0, 0);
            a1 = __builtin_amdgcn_mfma_f32_16x16x32_bf16(ag2, b2, a1, 0, 0, 0);
            a1 = __builtin_amdgcn_mfma_f32_16x16x32_bf16(ag3, b3, a1, 0, 0, 0);
#pragma unroll
            for (int q = 0; q < 4; ++q) {
                float v = a0[q];
                sE[0][q] += exp2_raw(v);
                float n0 = fmaxf(c0[0][q], v);                       // top-2 insert:
                c1[0][q] = __builtin_amdgcn_fmed3f(c0[0][q], c1[0][q], v); // 2nd = median
                c0[0][q] = n0;
                v = a1[q];
                sE[1][q] += exp2_raw(v);
                n0 = fmaxf(c0[1][q], v);
                c1[1][q] = __builtin_amdgcn_fmed3f(c0[1][q], c1[1][q], v);
                c0[1][q] = n0;
            }
        }
        __syncthreads();
    }

    // per row-set: merge top-2 across the 16-lane r-group (-> top-2 per chunk),
    // reduce sE across the 16-lane group, write outputs
#pragma unroll
    for (int s2 = 0; s2 < 2; ++s2) {
#pragma unroll
        for (int o = 1; o <= 8; o <<= 1) {
#pragma unroll
            for (int q = 0; q < 4; ++q) {
                float o0 = __shfl_xor(c0[s2][q], o, 64);
                float o1 = __shfl_xor(c1[s2][q], o, 64);
                float n0 = fmaxf(c0[s2][q], o0);
                float n1 = fmaxf(fminf(c0[s2][q], o0), fmaxf(c1[s2][q], o1));
                c0[s2][q] = n0;
                c1[s2][q] = n1;
            }
        }
#pragma unroll
        for (int o = 1; o <= 8; o <<= 1)
#pragma unroll
            for (int q = 0; q < 4; ++q)
                sE[s2][q] += __shfl_xor(sE[s2][q], o, 64);

        const int rowbase = i0 + s2 * 64 + w * 16 + p * 4;
        if (r == 0) {
#pragma unroll
            for (int q = 0; q < 4; ++q) {
                float2 v2 = make_float2(c0[s2][q], c1[s2][q]);
                *(float2*)(ct + (size_t)(rowbase + q) * (NC * CPC) + by * CPC) = v2;
                cs[(size_t)(rowbase + q) * NC + by] = sE[s2][q];
            }
        }
    }
}

// ---------- kernel 3: bitonic merge per row + global accumulate ----------
// One row per wave; 64 candidates = 1/lane. Bitonic descending sort across
// the wave (21 parallel compare-exchange steps, no divergence), then
// topsum = sum of ranks 1..16 (rank 0 = diagonal, dropped). Block partial
// summed in fixed order; one atomicAdd(out) per block.
__global__ __launch_bounds__(256) void k_merge(const float* __restrict__ cs,
                                               const float* __restrict__ ct,
                                               float* __restrict__ out) {
    __shared__ float sh[4];
    const int w = threadIdx.x >> 6, l = threadIdx.x & 63;
    const int row = blockIdx.x * 4 + w;

    // lse = log(sum of per-chunk exp-sums); values bounded (2^acc <= 2.72)
    float s = (l < NC) ? cs[(size_t)row * NC + l] : 0.f;
#pragma unroll
    for (int o = 1; o <= 32; o <<= 1) s += __shfl_xor(s, o, 64);
    float lse = logf(s);

    // bitonic descending sort of the 64 candidates
    float v = ct[(size_t)row * (NC * CPC) + l];
#pragma unroll
    for (int k = 2; k <= 64; k <<= 1) {
#pragma unroll
        for (int j = k >> 1; j > 0; j >>= 1) {
            float ov = __shfl_xor(v, j, 64);
            bool up = ((l & k) == 0);
            bool lower = ((l & j) == 0);
            float mn = fminf(v, ov), mx = fmaxf(v, ov);
            v = (up == lower) ? mx : mn;
        }
    }

    // sum of ranks 1..16 (rank = lane after descending sort)
    float t = (l >= 1 && l <= KSEL) ? v : 0.f;
#pragma unroll
    for (int o = 1; o <= 32; o <<= 1) t += __shfl_xor(t, o, 64);

    if (l == 0) sh[w] = (float)KSEL * lse - LN2 * t;
    __syncthreads();
    if (threadIdx.x == 0)
        atomicAdd(out, (sh[0] + sh[1]) + (sh[2] + sh[3]));
}

extern "C" void kernel_launch(void* const* d_in, const int* in_sizes, int n_in,
                              void* d_out, int out_size, void* d_ws, size_t ws_size,
                              hipStream_t stream) {
    const float* x = (const float*)d_in[0];
    float* out = (float*)d_out;

    unsigned short* xnA = (unsigned short*)d_ws;                // 2 MB (scaled)
    unsigned short* xnB = xnA + (size_t)N * D;                  // 2 MB
    float* cs = (float*)((char*)d_ws + (4u << 20));             // 1 MB
    float* ct = cs + (size_t)N * NC;                            // 2 MB

    k_normalize<<<N / 4, 256, 0, stream>>>(x, xnA, xnB, out);
    k_tiles<<<dim3(N / BM, NC), 256, 0, stream>>>(xnA, xnB, cs, ct);
    k_merge<<<N / 4, 256, 0, stream>>>(cs, ct, out);
}

// Round 12
// 66.591 us; speedup vs baseline: 1.3206x; 1.3206x over previous
//
#include <hip/hip_runtime.h>
#include <math.h>

#define N 8192
#define D 128
#define KSEL 16
#define CH 512            // columns per chunk (per block)
#define NC (N / CH)       // 16 chunks per row
#define BM 128            // rows per block (4 waves x 2 sets x 16)
#define PH 8              // phases per chunk, 64 cols each
#define CPC 4             // candidates per chunk per row (top-2 x 2 groups)
#define NEG_INF_F (-1e30f)
#define LOG2E 1.44269504f
#define LN2 0.69314718f

typedef __attribute__((ext_vector_type(8))) short short8;
typedef __attribute__((ext_vector_type(4))) float f32x4;
typedef __attribute__((ext_vector_type(2))) unsigned short ush2;

static __device__ __forceinline__ unsigned short f2bf(float f) {
    unsigned u = __float_as_uint(f);
    u += 0x7FFF + ((u >> 16) & 1);          // RNE
    return (unsigned short)(u >> 16);
}

// raw v_exp_f32 (2^x). Domain here is |x| <= ~1.45, so the compiler's
// denormal-range fixup (cmp/cndmask/ldexp around v_exp_f32) is dead weight.
static __device__ __forceinline__ float exp2_raw(float x) {
    float r;
    asm("v_exp_f32 %0, %1" : "=v"(r) : "v"(x));
    return r;
}

// async global->LDS, 16B per lane, LDS dest = uniform base + lane*16
#define GLOAD_LDS(gsrc, ldst)                                                     \
    __builtin_amdgcn_global_load_lds(                                             \
        (const __attribute__((address_space(1))) unsigned int*)(const void*)(gsrc),\
        (__attribute__((address_space(3))) unsigned int*)(void*)(ldst), 16, 0, 0)

// ---------- kernel 1: normalize rows; xnB = bf16(xn), xnA = bf16(log2e*xn) ----------
__global__ void k_normalize(const float* __restrict__ x,
                            unsigned short* __restrict__ xnA,
                            unsigned short* __restrict__ xnB,
                            float* __restrict__ out) {
    if (blockIdx.x == 0 && threadIdx.x == 0) out[0] = 0.f;   // accumulator init
    int row = blockIdx.x * 4 + (threadIdx.x >> 6);
    int lane = threadIdx.x & 63;
    const float2* x2 = (const float2*)(x + (size_t)row * D);
    float2 a = x2[lane];
    float s = fmaf(a.x, a.x, a.y * a.y);
#pragma unroll
    for (int off = 32; off > 0; off >>= 1) s += __shfl_xor(s, off, 64);
    float inv = rsqrtf(s);
    ush2 hb, ha;
    hb.x = f2bf(a.x * inv);
    hb.y = f2bf(a.y * inv);
    ha.x = f2bf(a.x * inv * LOG2E);
    ha.y = f2bf(a.y * inv * LOG2E);
    *(ush2*)(xnB + (size_t)row * D + lane * 2) = hb;
    *(ush2*)(xnA + (size_t)row * D + lane * 2) = ha;
}

// ---------- kernel 2: LDS-staged MFMA, 2 A-row-sets per wave ----------
// Round-10 structure (proven 40.7 us, no spill at launch_bounds(256,4)).
// Changes vs round 10 ONLY: (a) bare v_exp_f32 (fixup elided, domain-safe);
// (b) top-2 insert via max+fmed3 (2 insts). Per-elem epilogue ~9 -> 4 insts.
// Each B fragment (one ds_read_b128) feeds TWO MFMAs (row-sets +0 and +64).
// acc = log2e*S; exp-sum is bare exp2; top-k order unchanged (merge applies
// ln2). Emits top-2 per 8-lane group (4 candidates/chunk/row -> 64/row).
// Diagonal stays IN exp-sum (reference keeps self) and IN candidates
// (scaled S_ii ~ 1.44 is the global candidate max; merge drops rank 0).
__global__ __launch_bounds__(256, 4) void k_tiles(const unsigned short* __restrict__ xnA,
                                                  const unsigned short* __restrict__ xnB,
                                                  float* __restrict__ cs,
                                                  float* __restrict__ ct) {
    // [buf][tile][slice][lane][8 bf16] = 32 KB
    __shared__ unsigned short Bsh[2][4][4][64][8];

    const int tid = threadIdx.x;
    const int w = tid >> 6;
    const int l = tid & 63;
    const int r = l & 15;                    // col-within-tile / A-row lane
    const int p = l >> 4;                    // k-group; output rows p*4+q
    const int i0 = blockIdx.x * BM;
    const int j0 = blockIdx.y * CH;
    const int by = blockIdx.y;

    // A fragments, two row-sets: rows i0 + set*64 + w*16 + r
    const unsigned short* ap = xnA + (size_t)(i0 + w * 16 + r) * D + p * 8;
    short8 af0 = *(const short8*)(ap);
    short8 af1 = *(const short8*)(ap + 32);
    short8 af2 = *(const short8*)(ap + 64);
    short8 af3 = *(const short8*)(ap + 96);
    const unsigned short* gp = ap + (size_t)64 * D;
    short8 ag0 = *(const short8*)(gp);
    short8 ag1 = *(const short8*)(gp + 32);
    short8 ag2 = *(const short8*)(gp + 64);
    short8 ag3 = *(const short8*)(gp + 96);

    float sE[2][4], c0[2][4], c1[2][4];
#pragma unroll
    for (int s2 = 0; s2 < 2; ++s2)
#pragma unroll
        for (int q = 0; q < 4; ++q) {
            sE[s2][q] = 0.f;
            c0[s2][q] = c1[s2][q] = NEG_INF_F;
        }

    // staging source: wave w stages slice w; lane l fetches
    // B[j0 + ph*64 + tile*16 + (l&15)][k = (l>>4)*8 + w*32]
    const unsigned short* sbase = xnB + (size_t)(j0 + r) * D + p * 8 + w * 32;

    // prologue: stage phase 0 into buf 0
#pragma unroll
    for (int tt = 0; tt < 4; ++tt)
        GLOAD_LDS(sbase + (size_t)tt * (16 * D), &Bsh[0][tt][w][0][0]);
    __syncthreads();

    for (int ph = 0; ph < PH; ++ph) {
        const int buf = ph & 1;
        if (ph < PH - 1) {
            const unsigned short* s1 = sbase + (size_t)(ph + 1) * (64 * D);
#pragma unroll
            for (int tt = 0; tt < 4; ++tt)
                GLOAD_LDS(s1 + (size_t)tt * (16 * D), &Bsh[buf ^ 1][tt][w][0][0]);
        }
#pragma unroll
        for (int tt = 0; tt < 4; ++tt) {
            short8 b0 = *(const short8*)&Bsh[buf][tt][0][l][0];
            short8 b1 = *(const short8*)&Bsh[buf][tt][1][l][0];
            short8 b2 = *(const short8*)&Bsh[buf][tt][2][l][0];
            short8 b3 = *(const short8*)&Bsh[buf][tt][3][l][0];
            f32x4 a0 = {0.f, 0.f, 0.f, 0.f};
            f32x4 a1 = {0.f, 0.f, 0.f, 0.f};
            a0 = __builtin_amdgcn_mfma_f32_16x16x32_bf16(af0, b0, a0, 0, 0, 0);
            a0 = __builtin_amdgcn_mfma_f32_16x16x32_bf16(af1, b1, a0, 0, 0, 0);
            a0 = __builtin_amdgcn_mfma_f32_16x16x32_bf16(af2, b2, a0, 0, 0, 0);
            a0 = __builtin_amdgcn_mfma_f32_16x16x32_bf16(af3, b3, a0, 0, 0, 0);
            a1 = __builtin_amdgcn_mfma_f32_16x16x32_bf16(ag0, b0, a1, 0, 0, 0);
            a1 = __builtin_amdgcn_mfma_f32_16x16x32_bf16(ag1, b1, a1, 0, 0, 0);
            a1 = __builtin_amdgcn_mfma_f32_16x16x32_bf16(ag2, b2, a1, 0, 0, 0);
            a1 = __builtin_amdgcn_mfma_f32_16x16x32_bf16(ag3, b3, a1, 0, 0, 0);
#pragma unroll
            for (int q = 0; q < 4; ++q) {
                float v = a0[q];
                sE[0][q] += exp2_raw(v);
                float n0 = fmaxf(c0[0][q], v);                            // top-2:
                c1[0][q] = __builtin_amdgcn_fmed3f(c0[0][q], c1[0][q], v); // 2nd = med3
                c0[0][q] = n0;
                v = a1[q];
                sE[1][q] += exp2_raw(v);
                n0 = fmaxf(c0[1][q], v);
                c1[1][q] = __builtin_amdgcn_fmed3f(c0[1][q], c1[1][q], v);
                c0[1][q] = n0;
            }
        }
        __syncthreads();
    }

    // per row-set: merge top-2 across 8-lane subgroups (-> top-2 per 256 cols),
    // reduce sE across the 16-lane group, write outputs
#pragma unroll
    for (int s2 = 0; s2 < 2; ++s2) {
#pragma unroll
        for (int o = 1; o <= 4; o <<= 1) {
#pragma unroll
            for (int q = 0; q < 4; ++q) {
                float o0 = __shfl_xor(c0[s2][q], o, 64);
                float o1 = __shfl_xor(c1[s2][q], o, 64);
                float m0 = fminf(c0[s2][q], o0);
                c0[s2][q] = fmaxf(c0[s2][q], o0);
                c1[s2][q] = fmaxf(c1[s2][q], m0);
                c1[s2][q] = fmaxf(c1[s2][q], o1);   // o1 <= o0, can't beat c0
            }
        }
#pragma unroll
        for (int o = 1; o <= 8; o <<= 1)
#pragma unroll
            for (int q = 0; q < 4; ++q)
                sE[s2][q] += __shfl_xor(sE[s2][q], o, 64);

        const int rowbase = i0 + s2 * 64 + w * 16 + p * 4;
        if ((r & 7) == 0) {
            int rG = r >> 3;                  // 2 groups per row
#pragma unroll
            for (int q = 0; q < 4; ++q) {
                float2 v2 = make_float2(c0[s2][q], c1[s2][q]);
                *(float2*)(ct + (size_t)(rowbase + q) * (NC * CPC) + by * CPC + rG * 2) = v2;
            }
        }
        if (r == 0) {
#pragma unroll
            for (int q = 0; q < 4; ++q)
                cs[(size_t)(rowbase + q) * NC + by] = sE[s2][q];
        }
    }
}

// ---------- kernel 3: bitonic merge per row + global accumulate ----------
// One row per wave; 64 candidates = 1/lane. Bitonic descending sort across
// the wave (21 parallel compare-exchange steps, no divergence), then
// topsum = sum of ranks 1..16 (rank 0 = diagonal, dropped). Block partial
// summed in fixed order; one atomicAdd(out) per block.
__global__ __launch_bounds__(256) void k_merge(const float* __restrict__ cs,
                                               const float* __restrict__ ct,
                                               float* __restrict__ out) {
    __shared__ float sh[4];
    const int w = threadIdx.x >> 6, l = threadIdx.x & 63;
    const int row = blockIdx.x * 4 + w;

    // lse = log(sum of per-chunk exp-sums); values bounded (2^acc <= 2.72)
    float s = cs[(size_t)row * NC + (l & 15)];
#pragma unroll
    for (int o = 1; o <= 8; o <<= 1) s += __shfl_xor(s, o, 64);
    float lse = logf(s);

    // bitonic descending sort of the 64 candidates
    float v = ct[(size_t)row * (NC * CPC) + l];
#pragma unroll
    for (int k = 2; k <= 64; k <<= 1) {
#pragma unroll
        for (int j = k >> 1; j > 0; j >>= 1) {
            float ov = __shfl_xor(v, j, 64);
            bool up = ((l & k) == 0);
            bool lower = ((l & j) == 0);
            float mn = fminf(v, ov), mx = fmaxf(v, ov);
            v = (up == lower) ? mx : mn;
        }
    }

    // sum of ranks 1..16 (rank = lane after descending sort)
    float t = (l >= 1 && l <= KSEL) ? v : 0.f;
#pragma unroll
    for (int o = 1; o <= 32; o <<= 1) t += __shfl_xor(t, o, 64);

    if (l == 0) sh[w] = (float)KSEL * lse - LN2 * t;
    __syncthreads();
    if (threadIdx.x == 0)
        atomicAdd(out, (sh[0] + sh[1]) + (sh[2] + sh[3]));
}

extern "C" void kernel_launch(void* const* d_in, const int* in_sizes, int n_in,
                              void* d_out, int out_size, void* d_ws, size_t ws_size,
                              hipStream_t stream) {
    const float* x = (const float*)d_in[0];
    float* out = (float*)d_out;

    unsigned short* xnA = (unsigned short*)d_ws;                // 2 MB (scaled)
    unsigned short* xnB = xnA + (size_t)N * D;                  // 2 MB
    float* cs = (float*)((char*)d_ws + (4u << 20));             // 512 KB
    float* ct = cs + (size_t)N * NC;                            // 2 MB

    k_normalize<<<N / 4, 256, 0, stream>>>(x, xnA, xnB, out);
    k_tiles<<<dim3(N / BM, NC), 256, 0, stream>>>(xnA, xnB, cs, ct);
    k_merge<<<N / 4, 256, 0, stream>>>(cs, ct, out);
}